// Round 6
// baseline (622.283 us; speedup 1.0000x reference)
//
#include <hip/hip_runtime.h>
#include <hip/hip_bf16.h>
#include <cstdint>

#define M_ROWS 131072
#define D_DIM  256
#define K_CL   512

typedef __attribute__((ext_vector_type(4))) float  f4;
typedef __attribute__((ext_vector_type(8))) short  bfrag;   // 8 bf16 (4 VGPRs)
typedef __attribute__((ext_vector_type(4))) float  ffrag;   // 4 f32 acc

#define MFMA16(A,B,C) __builtin_amdgcn_mfma_f32_16x16x32_bf16((A),(B),(C),0,0,0)

__device__ __forceinline__ ffrag fzero() {
    ffrag z;
    z[0] = 0.f; z[1] = 0.f; z[2] = 0.f; z[3] = 0.f;
    return z;
}

__device__ __forceinline__ unsigned short f2bf(float f) {
    unsigned int u = __float_as_uint(f);
    u += 0x7FFFu + ((u >> 16) & 1u);          // round-to-nearest-even
    return (unsigned short)(u >> 16);
}
__device__ __forceinline__ float bf2f(unsigned short u) {
    return __uint_as_float(((unsigned int)u) << 16);
}

// ---------------------------------------------------------------------------
// Prep: cluster_center f32 [512][256] -> Cb bf16 [512][256], Ct bf16 [256][512],
// c_sq[512] (sum of squares of the bf16-rounded values).
// ---------------------------------------------------------------------------
__global__ void prep_kernel(const float* __restrict__ C,
                            unsigned short* __restrict__ Cb,
                            unsigned short* __restrict__ Ct,
                            float* __restrict__ csq)
{
    __shared__ unsigned short lds[64 * 264];
    const int tid = threadIdx.x;          // 256 threads
    const int kb  = blockIdx.x * 64;      // 8 blocks
    const int r   = tid >> 2;
    const int q   = tid & 3;

    const float* cr = C + (size_t)(kb + r) * D_DIM;
    float s = 0.f;
    #pragma unroll
    for (int i = 0; i < 16; ++i) {
        const int j = q * 16 + i;
        f4 v = *(const f4*)(cr + j * 4);
        unsigned short u0 = f2bf(v[0]), u1 = f2bf(v[1]), u2 = f2bf(v[2]), u3 = f2bf(v[3]);
        *(ushort4*)(Cb + (size_t)(kb + r) * D_DIM + j * 4) = make_ushort4(u0, u1, u2, u3);
        *(ushort4*)(lds + r * 264 + j * 4)                  = make_ushort4(u0, u1, u2, u3);
        float f0 = bf2f(u0), f1 = bf2f(u1), f2_ = bf2f(u2), f3 = bf2f(u3);
        s += f0 * f0 + f1 * f1 + f2_ * f2_ + f3 * f3;
    }
    s += __shfl_xor(s, 1, 64);
    s += __shfl_xor(s, 2, 64);
    if (q == 0) csq[kb + r] = s;
    __syncthreads();

    #pragma unroll
    for (int c = 0; c < 16; ++c) {
        ushort4 p = make_ushort4(lds[(c * 4 + 0) * 264 + tid],
                                 lds[(c * 4 + 1) * 264 + tid],
                                 lds[(c * 4 + 2) * 264 + tid],
                                 lds[(c * 4 + 3) * 264 + tid]);
        *(ushort4*)(Ct + (size_t)tid * K_CL + kb + c * 4) = p;
    }
}

// ---------------------------------------------------------------------------
// K1: LayerNorm. One wave per row. Writes xn bf16 [M][256] + xsq f32 [M].
// ---------------------------------------------------------------------------
__global__ __launch_bounds__(256)
void ln_kernel(const float* __restrict__ x,
               const float* __restrict__ lnw,
               const float* __restrict__ lnb,
               unsigned short* __restrict__ xn,
               float* __restrict__ xsq)
{
    const int row = blockIdx.x * 4 + (threadIdx.x >> 6);
    const int l   = threadIdx.x & 63;

    f4 v = *(const f4*)(x + (size_t)row * D_DIM + l * 4);
    float sum = v[0] + v[1] + v[2] + v[3];
    float ss  = v[0] * v[0] + v[1] * v[1] + v[2] * v[2] + v[3] * v[3];
    #pragma unroll
    for (int msk = 1; msk < 64; msk <<= 1) {
        sum += __shfl_xor(sum, msk, 64);
        ss  += __shfl_xor(ss,  msk, 64);
    }
    const float mean = sum * (1.0f / 256.0f);
    float var = ss * (1.0f / 256.0f) - mean * mean;
    var = fmaxf(var, 0.0f);
    const float inv = 1.0f / (sqrtf(var) + 1e-5f);

    f4 wv = *(const f4*)(lnw + l * 4);
    f4 bv = *(const f4*)(lnb + l * 4);
    float a0 = (v[0] - mean) * inv * wv[0] + bv[0];
    float a1 = (v[1] - mean) * inv * wv[1] + bv[1];
    float a2 = (v[2] - mean) * inv * wv[2] + bv[2];
    float a3 = (v[3] - mean) * inv * wv[3] + bv[3];
    unsigned short u0 = f2bf(a0), u1 = f2bf(a1), u2 = f2bf(a2), u3 = f2bf(a3);
    *(ushort4*)(xn + (size_t)row * D_DIM + l * 4) = make_ushort4(u0, u1, u2, u3);

    float c0 = bf2f(u0), c1 = bf2f(u1), c2 = bf2f(u2), c3 = bf2f(u3);
    float xs = c0 * c0 + c1 * c1 + c2 * c2 + c3 * c3;
    #pragma unroll
    for (int msk = 1; msk < 64; msk <<= 1) xs += __shfl_xor(xs, msk, 64);
    if (l == 0) xsq[row] = xs;
}

// ---------------------------------------------------------------------------
// K2: distances + softmax. 4 independent waves per block, 16 rows per wave.
// Zero LDS, zero barriers. Swapped-operand MFMA: lane (g,cl) holds
// S[m0+cl][nt*16+g*4+r]. All stores are dwordx4.
// ---------------------------------------------------------------------------
__global__ __launch_bounds__(256)
void dist_kernel(const unsigned short* __restrict__ xn,
                 const float* __restrict__ xsq,
                 const unsigned short* __restrict__ Cb,
                 const float* __restrict__ csq,
                 float* __restrict__ out0,   // x_distance  [M][512]
                 float* __restrict__ out1)   // assign      [M][512]
{
    const int tid = threadIdx.x;
    const int l   = tid & 63;
    const int g   = l >> 4;
    const int cl  = l & 15;
    const int m0  = (blockIdx.x * 4 + (tid >> 6)) * 16;

#define LOADB(BUF, NT) {                                                        \
    const unsigned short* bp_ = Cb + ((NT) * 16 + cl) * D_DIM + g * 8;          \
    _Pragma("unroll")                                                           \
    for (int i_ = 0; i_ < 8; ++i_) (BUF)[i_] = *(const bfrag*)(bp_ + i_ * 32); }

#define TILE1(BUF, NT) {                                                        \
    acc[NT] = MFMA16((BUF)[0], xnf[0], fzero());                                \
    _Pragma("unroll")                                                           \
    for (int i_ = 1; i_ < 8; ++i_)                                              \
        acc[NT] = MFMA16((BUF)[i_], xnf[i_], acc[NT]); }

    // ---- xn A-operand frags: lane cl carries xn row (m0+cl) directly ----
    bfrag xnf[8];
    {
        const unsigned short* xr = xn + (size_t)(m0 + cl) * D_DIM + g * 8;
        #pragma unroll
        for (int ks = 0; ks < 8; ++ks)
            xnf[ks] = *(const bfrag*)(xr + ks * 32);
    }
    const float xsqv = xsq[m0 + cl];

    // ---- GEMM1: 32 output tiles, double-buffered B stream ----
    ffrag acc[32];
    bfrag b0[8], b1[8];
    LOADB(b0, 0);
    LOADB(b1, 1);
    TILE1(b0, 0);  LOADB(b0, 2);
    TILE1(b1, 1);  LOADB(b1, 3);
    TILE1(b0, 2);  LOADB(b0, 4);
    TILE1(b1, 3);  LOADB(b1, 5);
    TILE1(b0, 4);  LOADB(b0, 6);
    TILE1(b1, 5);  LOADB(b1, 7);
    TILE1(b0, 6);  LOADB(b0, 8);
    TILE1(b1, 7);  LOADB(b1, 9);
    TILE1(b0, 8);  LOADB(b0, 10);
    TILE1(b1, 9);  LOADB(b1, 11);
    TILE1(b0, 10); LOADB(b0, 12);
    TILE1(b1, 11); LOADB(b1, 13);
    TILE1(b0, 12); LOADB(b0, 14);
    TILE1(b1, 13); LOADB(b1, 15);
    TILE1(b0, 14); LOADB(b0, 16);
    TILE1(b1, 15); LOADB(b1, 17);
    TILE1(b0, 16); LOADB(b0, 18);
    TILE1(b1, 17); LOADB(b1, 19);
    TILE1(b0, 18); LOADB(b0, 20);
    TILE1(b1, 19); LOADB(b1, 21);
    TILE1(b0, 20); LOADB(b0, 22);
    TILE1(b1, 21); LOADB(b1, 23);
    TILE1(b0, 22); LOADB(b0, 24);
    TILE1(b1, 23); LOADB(b1, 25);
    TILE1(b0, 24); LOADB(b0, 26);
    TILE1(b1, 25); LOADB(b1, 27);
    TILE1(b0, 26); LOADB(b0, 28);
    TILE1(b1, 27); LOADB(b1, 29);
    TILE1(b0, 28); LOADB(b0, 30);
    TILE1(b1, 29); LOADB(b1, 31);
    TILE1(b0, 30);
    TILE1(b1, 31);

    // ---- distances + out0 (dwordx4) + row-sum ----
    float dsum = 0.f;
    #pragma unroll
    for (int nt = 0; nt < 32; ++nt) {
        f4 cs = *(const f4*)(csq + nt * 16 + g * 4);
        f4 dv;
        #pragma unroll
        for (int r = 0; r < 4; ++r) {
            float d2 = xsqv + cs[r] - 2.0f * acc[nt][r];
            dv[r] = sqrtf(fmaxf(d2, 0.0f));
            acc[nt][r] = dv[r];
        }
        *(f4*)(out0 + (size_t)(m0 + cl) * K_CL + nt * 16 + g * 4) = dv;
        dsum += dv[0] + dv[1] + dv[2] + dv[3];
    }
    dsum += __shfl_xor(dsum, 16, 64);
    dsum += __shfl_xor(dsum, 32, 64);
    const float sc = 16384.0f / dsum;   // alpha * K / sum_d = 32/mean_d

    // ---- softmax (no max-sub: logits ~ -32, f32-safe) ----
    float es = 0.f;
    #pragma unroll
    for (int nt = 0; nt < 32; ++nt)
        #pragma unroll
        for (int r = 0; r < 4; ++r) {
            float p = __expf(-acc[nt][r] * sc);
            acc[nt][r] = p;
            es += p;
        }
    es += __shfl_xor(es, 16, 64);
    es += __shfl_xor(es, 32, 64);
    const float rn = 1.0f / es;

    #pragma unroll
    for (int nt = 0; nt < 32; ++nt) {
        f4 av;
        #pragma unroll
        for (int r = 0; r < 4; ++r) av[r] = acc[nt][r] * rn;
        *(f4*)(out1 + (size_t)(m0 + cl) * K_CL + nt * 16 + g * 4) = av;
    }

#undef LOADB
#undef TILE1
}

// ---------------------------------------------------------------------------
// K3: x_rec = assign @ C. 4 waves, 32 rows/block; assign f32 read from out1,
// converted to bf16 into LDS; Ct streamed with double-buffered pipeline.
// ---------------------------------------------------------------------------
__global__ __launch_bounds__(256)
void rec_kernel(const float* __restrict__ out1,
                const unsigned short* __restrict__ Ct,
                float* __restrict__ out2)    // x_rec [M][256]
{
    __shared__ __align__(16) unsigned short as_s[32 * 520];

    const int tid = threadIdx.x;
    const int w   = tid >> 6;
    const int l   = tid & 63;
    const int g   = l >> 4;
    const int cl  = l & 15;
    const int m0  = blockIdx.x * 32;
    const int db  = w * 64;

    // ---- stage assign f32 -> bf16 LDS [32][520] ----
    {
        const int row = tid >> 3, q = tid & 7;
        const float* ar = out1 + (size_t)(m0 + row) * K_CL + q * 4;
        #pragma unroll
        for (int i = 0; i < 16; ++i) {
            f4 v = *(const f4*)(ar + i * 32);
            *(ushort4*)(as_s + row * 520 + q * 4 + i * 32) =
                make_ushort4(f2bf(v[0]), f2bf(v[1]), f2bf(v[2]), f2bf(v[3]));
        }
    }
    __syncthreads();

#define LOADB2(BUF, Q) {                                                        \
    const unsigned short* bp_ = Ct + (size_t)(db + ((Q) & 3) * 16 + cl) * K_CL  \
                                + ((Q) >> 2) * 256 + g * 8;                     \
    _Pragma("unroll")                                                           \
    for (int i_ = 0; i_ < 8; ++i_) (BUF)[i_] = *(const bfrag*)(bp_ + i_ * 32); }

#define LOADA2(KH) {                                                            \
    _Pragma("unroll")                                                           \
    for (int i_ = 0; i_ < 8; ++i_) {                                            \
        a2[0][i_] = *(const bfrag*)(as_s + (cl)      * 520 + (KH) * 256 + i_ * 32 + g * 8); \
        a2[1][i_] = *(const bfrag*)(as_s + (16 + cl) * 520 + (KH) * 256 + i_ * 32 + g * 8); } }

#define MFMA2(BUF, NT) {                                                        \
    _Pragma("unroll")                                                           \
    for (int i_ = 0; i_ < 8; ++i_) {                                            \
        acc2[0][NT] = MFMA16(a2[0][i_], (BUF)[i_], acc2[0][NT]);                \
        acc2[1][NT] = MFMA16(a2[1][i_], (BUF)[i_], acc2[1][NT]); } }

    ffrag acc2[2][4];
    #pragma unroll
    for (int rt = 0; rt < 2; ++rt)
        #pragma unroll
        for (int nt = 0; nt < 4; ++nt)
            acc2[rt][nt] = fzero();

    bfrag bA[8], bB[8];
    bfrag a2[2][8];
    LOADB2(bA, 0);
    LOADB2(bB, 1);
    LOADA2(0);
    MFMA2(bA, 0); LOADB2(bA, 2);
    MFMA2(bB, 1); LOADB2(bB, 3);
    MFMA2(bA, 2); LOADB2(bA, 4);
    MFMA2(bB, 3); LOADB2(bB, 5);
    LOADA2(1);
    MFMA2(bA, 0); LOADB2(bA, 6);
    MFMA2(bB, 1); LOADB2(bB, 7);
    MFMA2(bA, 2);
    MFMA2(bB, 3);

    #pragma unroll
    for (int rt = 0; rt < 2; ++rt)
        #pragma unroll
        for (int nt = 0; nt < 4; ++nt)
            #pragma unroll
            for (int r = 0; r < 4; ++r)
                out2[(size_t)(m0 + rt * 16 + g * 4 + r) * D_DIM + db + nt * 16 + cl]
                    = acc2[rt][nt][r];

#undef LOADB2
#undef LOADA2
#undef MFMA2
}

extern "C" void kernel_launch(void* const* d_in, const int* in_sizes, int n_in,
                              void* d_out, int out_size, void* d_ws, size_t ws_size,
                              hipStream_t stream)
{
    const float* x   = (const float*)d_in[0];
    const float* lnw = (const float*)d_in[1];
    const float* lnb = (const float*)d_in[2];
    const float* C   = (const float*)d_in[3];

    float* out0 = (float*)d_out;
    float* out1 = out0 + (size_t)M_ROWS * K_CL;
    float* out2 = out1 + (size_t)M_ROWS * K_CL;

    unsigned short* Cb = (unsigned short*)d_ws;                       // 512*256 bf16
    unsigned short* Ct = Cb + (size_t)K_CL * D_DIM;                   // 256*512 bf16
    float*          cs = (float*)((char*)d_ws + 2u * K_CL * D_DIM * 2u); // [512] f32

    // xn bf16 [M][256] + xsq f32 [M] live in the (dead-until-K3) out2 region:
    // 67.1 MB + 0.5 MB < 134.2 MB. K3 reads only out1/Ct and overwrites out2.
    unsigned short* xn  = (unsigned short*)out2;
    float*          xsq = (float*)((char*)out2 + (size_t)M_ROWS * D_DIM * 2);

    prep_kernel<<<8, 256, 0, stream>>>(C, Cb, Ct, cs);
    ln_kernel<<<M_ROWS / 4, 256, 0, stream>>>(x, lnw, lnb, xn, xsq);
    dist_kernel<<<M_ROWS / 64, 256, 0, stream>>>(xn, xsq, Cb, cs, out0, out1);
    rec_kernel<<<M_ROWS / 32, 256, 0, stream>>>(out1, Ct, out2);
}

// Round 7
// 350.728 us; speedup vs baseline: 1.7743x; 1.7743x over previous
//
#include <hip/hip_runtime.h>
#include <hip/hip_bf16.h>
#include <cstdint>

#define M_ROWS 131072
#define D_DIM  256
#define K_CL   512

typedef __attribute__((ext_vector_type(4))) float  f4;
typedef __attribute__((ext_vector_type(8))) short  bfrag;   // 8 bf16 (4 VGPRs)
typedef __attribute__((ext_vector_type(4))) float  ffrag;   // 4 f32 acc

#define MFMA16(A,B,C) __builtin_amdgcn_mfma_f32_16x16x32_bf16((A),(B),(C),0,0,0)

__device__ __forceinline__ ffrag fzero() {
    ffrag z;
    z[0] = 0.f; z[1] = 0.f; z[2] = 0.f; z[3] = 0.f;
    return z;
}

__device__ __forceinline__ unsigned short f2bf(float f) {
    unsigned int u = __float_as_uint(f);
    u += 0x7FFFu + ((u >> 16) & 1u);          // round-to-nearest-even
    return (unsigned short)(u >> 16);
}
__device__ __forceinline__ float bf2f(unsigned short u) {
    return __uint_as_float(((unsigned int)u) << 16);
}

// ---------------------------------------------------------------------------
// Prep: cluster_center f32 [512][256] -> Cb bf16 [512][256], Ct bf16 [256][512],
// c_sq[512] (sum of squares of the bf16-rounded values).
// ---------------------------------------------------------------------------
__global__ void prep_kernel(const float* __restrict__ C,
                            unsigned short* __restrict__ Cb,
                            unsigned short* __restrict__ Ct,
                            float* __restrict__ csq)
{
    __shared__ unsigned short lds[64 * 264];
    const int tid = threadIdx.x;          // 256 threads
    const int kb  = blockIdx.x * 64;      // 8 blocks
    const int r   = tid >> 2;
    const int q   = tid & 3;

    const float* cr = C + (size_t)(kb + r) * D_DIM;
    float s = 0.f;
    #pragma unroll
    for (int i = 0; i < 16; ++i) {
        const int j = q * 16 + i;
        f4 v = *(const f4*)(cr + j * 4);
        unsigned short u0 = f2bf(v[0]), u1 = f2bf(v[1]), u2 = f2bf(v[2]), u3 = f2bf(v[3]);
        *(ushort4*)(Cb + (size_t)(kb + r) * D_DIM + j * 4) = make_ushort4(u0, u1, u2, u3);
        *(ushort4*)(lds + r * 264 + j * 4)                  = make_ushort4(u0, u1, u2, u3);
        float f0 = bf2f(u0), f1 = bf2f(u1), f2_ = bf2f(u2), f3 = bf2f(u3);
        s += f0 * f0 + f1 * f1 + f2_ * f2_ + f3 * f3;
    }
    s += __shfl_xor(s, 1, 64);
    s += __shfl_xor(s, 2, 64);
    if (q == 0) csq[kb + r] = s;
    __syncthreads();

    #pragma unroll
    for (int c = 0; c < 16; ++c) {
        ushort4 p = make_ushort4(lds[(c * 4 + 0) * 264 + tid],
                                 lds[(c * 4 + 1) * 264 + tid],
                                 lds[(c * 4 + 2) * 264 + tid],
                                 lds[(c * 4 + 3) * 264 + tid]);
        *(ushort4*)(Ct + (size_t)tid * K_CL + kb + c * 4) = p;
    }
}

// ---------------------------------------------------------------------------
// Fused: LN -> cdist -> softmax -> x_rec. 256 thr (4 waves), 32 rows/block.
// Swapped-operand MFMA: lane(g,cl) of wave w holds tile elem
// (row = rt*16+cl, col = w*128 + nt*16 + g*4 + r)  => dwordx4 stores, cheap
// row-softmax. xn re-read from LDS per col-tile (no held A array) => VGPR<=128
// for 4 blocks/CU. Simple loops; compiler schedules.
// ---------------------------------------------------------------------------
__global__ __launch_bounds__(256, 4)
void fused_kernel(const float* __restrict__ x,
                  const float* __restrict__ lnw,
                  const float* __restrict__ lnb,
                  const unsigned short* __restrict__ Cb,
                  const unsigned short* __restrict__ Ct,
                  const float* __restrict__ csq,
                  float* __restrict__ out0,   // x_distance  [M][512]
                  float* __restrict__ out1,   // assign      [M][512]
                  float* __restrict__ out2)   // x_rec       [M][256]
{
    __shared__ __align__(16) char smem[34432];
    // [0, 33280): xn_s [32][264] bf16 (16896B) UNION as_s [32][520] bf16 (33280B)
    // xn_s dead after GEMM1 (pre-barrier-2); as_s written after barrier 3.
    unsigned short* xn_s = (unsigned short*)smem;
    unsigned short* as_s = (unsigned short*)smem;
    float* red_a = (float*)(smem + 33280);    // [2][4][16] f32 (512B)
    float* red_b = (float*)(smem + 33792);    // [2][4][16] f32 (512B)
    float* xsq_s = (float*)(smem + 34304);    // [32]

    const int tid = threadIdx.x;
    const int w   = tid >> 6;        // wave 0..3
    const int l   = tid & 63;
    const int g   = l >> 4;          // 16-lane group
    const int cl  = l & 15;
    const int m0  = blockIdx.x * 32;
    const int nb  = w * 128;         // GEMM1 col base
    const int db  = w * 64;          // GEMM2 col base

    // ---- Phase A: LayerNorm (8 lanes per row) ----
    {
        const int rr = tid >> 3, sub = tid & 7;
        const float* xr = x + (size_t)(m0 + rr) * D_DIM;
        f4 xv[8];
        float sum = 0.f, ss = 0.f;
        #pragma unroll
        for (int i = 0; i < 8; ++i) {
            xv[i] = *(const f4*)(xr + (i * 8 + sub) * 4);
            #pragma unroll
            for (int c = 0; c < 4; ++c) { float v = xv[i][c]; sum += v; ss += v * v; }
        }
        #pragma unroll
        for (int msk = 1; msk < 8; msk <<= 1) {
            sum += __shfl_xor(sum, msk, 64);
            ss  += __shfl_xor(ss,  msk, 64);
        }
        const float mean = sum * (1.0f / 256.0f);
        float var = ss * (1.0f / 256.0f) - mean * mean;
        var = fmaxf(var, 0.0f);
        const float inv = 1.0f / (sqrtf(var) + 1e-5f);

        float xsq = 0.f;
        #pragma unroll
        for (int i = 0; i < 8; ++i) {
            f4 wv = *(const f4*)(lnw + (i * 8 + sub) * 4);
            f4 bv = *(const f4*)(lnb + (i * 8 + sub) * 4);
            float a0 = (xv[i][0] - mean) * inv * wv[0] + bv[0];
            float a1 = (xv[i][1] - mean) * inv * wv[1] + bv[1];
            float a2 = (xv[i][2] - mean) * inv * wv[2] + bv[2];
            float a3 = (xv[i][3] - mean) * inv * wv[3] + bv[3];
            unsigned short u0 = f2bf(a0), u1 = f2bf(a1), u2 = f2bf(a2), u3 = f2bf(a3);
            float c0 = bf2f(u0), c1 = bf2f(u1), c2 = bf2f(u2), c3 = bf2f(u3);
            xsq += c0 * c0 + c1 * c1 + c2 * c2 + c3 * c3;
            *(ushort4*)(xn_s + rr * 264 + (i * 8 + sub) * 4) = make_ushort4(u0, u1, u2, u3);
        }
        #pragma unroll
        for (int msk = 1; msk < 8; msk <<= 1) xsq += __shfl_xor(xsq, msk, 64);
        if (sub == 0) xsq_s[rr] = xsq;
    }
    __syncthreads();                               // barrier 1

    // ---- Phase A2: GEMM1 (swapped). acc[rt][nt] covers rows rt*16+cl,
    //      cols nb+nt*16+g*4+r. Cb streamed (4-frag dbuf), xn from LDS. ----
    ffrag acc[2][8];
    #pragma unroll
    for (int rt = 0; rt < 2; ++rt)
        #pragma unroll
        for (int nt = 0; nt < 8; ++nt) acc[rt][nt] = fzero();
    {
        bfrag cb[2][4];
        #pragma unroll
        for (int i = 0; i < 4; ++i)
            cb[0][i] = *(const bfrag*)(Cb + (nb + cl) * D_DIM + i * 32 + g * 8);
        #pragma unroll
        for (int bi = 0; bi < 16; ++bi) {
            const int nt = bi >> 1, kh = bi & 1;
            if (bi < 15) {
                const int nn = (bi + 1) >> 1, nk = (bi + 1) & 1;
                #pragma unroll
                for (int i = 0; i < 4; ++i)
                    cb[(bi + 1) & 1][i] = *(const bfrag*)
                        (Cb + (nb + nn * 16 + cl) * D_DIM + (nk * 4 + i) * 32 + g * 8);
            }
            #pragma unroll
            for (int rt = 0; rt < 2; ++rt)
                #pragma unroll
                for (int i = 0; i < 4; ++i) {
                    bfrag xf = *(const bfrag*)
                        (xn_s + (rt * 16 + cl) * 264 + (kh * 4 + i) * 32 + g * 8);
                    acc[rt][nt] = MFMA16(cb[bi & 1][i], xf, acc[rt][nt]);
                }
        }
    }

    // ---- Phase B: distances, dwordx4 stores, row sums ----
    float dsum[2];
    #pragma unroll
    for (int rt = 0; rt < 2; ++rt) {
        const float xsqv = xsq_s[rt * 16 + cl];
        dsum[rt] = 0.f;
        #pragma unroll
        for (int nt = 0; nt < 8; ++nt) {
            f4 cs = *(const f4*)(csq + nb + nt * 16 + g * 4);
            f4 dv;
            #pragma unroll
            for (int r = 0; r < 4; ++r) {
                float d2 = xsqv + cs[r] - 2.0f * acc[rt][nt][r];
                dv[r] = sqrtf(fmaxf(d2, 0.0f));
                acc[rt][nt][r] = dv[r];
            }
            *(f4*)(out0 + (size_t)(m0 + rt * 16 + cl) * K_CL + nb + nt * 16 + g * 4) = dv;
            dsum[rt] += dv[0] + dv[1] + dv[2] + dv[3];
        }
        dsum[rt] += __shfl_xor(dsum[rt], 16, 64);
        dsum[rt] += __shfl_xor(dsum[rt], 32, 64);
    }
    if (l < 16) {
        red_a[w * 16 + cl]      = dsum[0];
        red_a[64 + w * 16 + cl] = dsum[1];
    }
    __syncthreads();                               // barrier 2

    float sc[2];
    #pragma unroll
    for (int rt = 0; rt < 2; ++rt) {
        float t = red_a[rt * 64 + cl] + red_a[rt * 64 + 16 + cl]
                + red_a[rt * 64 + 32 + cl] + red_a[rt * 64 + 48 + cl];
        sc[rt] = 16384.0f / t;                     // alpha*K/sum = 32/mean_d
    }

    // ---- Phase D: exp + sumexp (no max-sub: logits ~ -32, f32-safe) ----
    float es[2];
    #pragma unroll
    for (int rt = 0; rt < 2; ++rt) {
        es[rt] = 0.f;
        #pragma unroll
        for (int nt = 0; nt < 8; ++nt)
            #pragma unroll
            for (int r = 0; r < 4; ++r) {
                float p = __expf(-acc[rt][nt][r] * sc[rt]);
                acc[rt][nt][r] = p;
                es[rt] += p;
            }
        es[rt] += __shfl_xor(es[rt], 16, 64);
        es[rt] += __shfl_xor(es[rt], 32, 64);
    }
    if (l < 16) {
        red_b[w * 16 + cl]      = es[0];
        red_b[64 + w * 16 + cl] = es[1];
    }
    __syncthreads();                               // barrier 3

    float rn[2];
    #pragma unroll
    for (int rt = 0; rt < 2; ++rt) {
        rn[rt] = 1.0f / (red_b[rt * 64 + cl] + red_b[rt * 64 + 16 + cl]
                       + red_b[rt * 64 + 32 + cl] + red_b[rt * 64 + 48 + cl]);
    }

    // ---- Phase D2: assign stores + bf16 into as_s (overwrites xn_s) ----
    #pragma unroll
    for (int rt = 0; rt < 2; ++rt)
        #pragma unroll
        for (int nt = 0; nt < 8; ++nt) {
            f4 av;
            #pragma unroll
            for (int r = 0; r < 4; ++r) av[r] = acc[rt][nt][r] * rn[rt];
            *(f4*)(out1 + (size_t)(m0 + rt * 16 + cl) * K_CL + nb + nt * 16 + g * 4) = av;
            unsigned int lo = (unsigned int)f2bf(av[0]) | ((unsigned int)f2bf(av[1]) << 16);
            unsigned int hi = (unsigned int)f2bf(av[2]) | ((unsigned int)f2bf(av[3]) << 16);
            *(uint2*)(as_s + (rt * 16 + cl) * 520 + nb + nt * 16 + g * 4) =
                make_uint2(lo, hi);
        }
    __syncthreads();                               // barrier 4

    // ---- Phase E: GEMM2 (swapped). acc2[rt][nt] covers rows rt*16+cl,
    //      d-cols db+nt*16+g*4+r. Ct streamed (4-frag dbuf), as from LDS. ----
    {
        ffrag acc2[2][4];
        #pragma unroll
        for (int rt = 0; rt < 2; ++rt)
            #pragma unroll
            for (int nt = 0; nt < 4; ++nt) acc2[rt][nt] = fzero();

        bfrag ct[2][4];
        #pragma unroll
        for (int i = 0; i < 4; ++i)
            ct[0][i] = *(const bfrag*)(Ct + (db + cl) * K_CL + i * 32 + g * 8);
        #pragma unroll
        for (int bi = 0; bi < 16; ++bi) {
            const int nt = bi >> 2, kb = bi & 3;
            if (bi < 15) {
                const int nn = (bi + 1) >> 2, nk = (bi + 1) & 3;
                #pragma unroll
                for (int i = 0; i < 4; ++i)
                    ct[(bi + 1) & 1][i] = *(const bfrag*)
                        (Ct + (db + nn * 16 + cl) * K_CL + (nk * 4 + i) * 32 + g * 8);
            }
            #pragma unroll
            for (int rt = 0; rt < 2; ++rt)
                #pragma unroll
                for (int i = 0; i < 4; ++i) {
                    bfrag af = *(const bfrag*)
                        (as_s + (rt * 16 + cl) * 520 + (kb * 4 + i) * 32 + g * 8);
                    acc2[rt][nt] = MFMA16(ct[bi & 1][i], af, acc2[rt][nt]);
                }
        }

        #pragma unroll
        for (int rt = 0; rt < 2; ++rt)
            #pragma unroll
            for (int nt = 0; nt < 4; ++nt) {
                f4 rv;
                #pragma unroll
                for (int r = 0; r < 4; ++r) rv[r] = acc2[rt][nt][r];
                *(f4*)(out2 + (size_t)(m0 + rt * 16 + cl) * D_DIM + db + nt * 16 + g * 4) = rv;
            }
    }
}

extern "C" void kernel_launch(void* const* d_in, const int* in_sizes, int n_in,
                              void* d_out, int out_size, void* d_ws, size_t ws_size,
                              hipStream_t stream)
{
    const float* x   = (const float*)d_in[0];
    const float* lnw = (const float*)d_in[1];
    const float* lnb = (const float*)d_in[2];
    const float* C   = (const float*)d_in[3];

    float* out0 = (float*)d_out;
    float* out1 = out0 + (size_t)M_ROWS * K_CL;
    float* out2 = out1 + (size_t)M_ROWS * K_CL;

    unsigned short* Cb = (unsigned short*)d_ws;                       // 512*256 bf16
    unsigned short* Ct = Cb + (size_t)K_CL * D_DIM;                   // 256*512 bf16
    float*          cs = (float*)((char*)d_ws + 2u * K_CL * D_DIM * 2u); // [512] f32

    prep_kernel<<<8, 256, 0, stream>>>(C, Cb, Ct, cs);
    fused_kernel<<<M_ROWS / 32, 256, 0, stream>>>(x, lnw, lnb, Cb, Ct, cs,
                                                  out0, out1, out2);
}

// Round 8
// 342.596 us; speedup vs baseline: 1.8164x; 1.0237x over previous
//
#include <hip/hip_runtime.h>
#include <hip/hip_bf16.h>
#include <cstdint>

#define M_ROWS 131072
#define D_DIM  256
#define K_CL   512

typedef __attribute__((ext_vector_type(4))) float  f4;
typedef __attribute__((ext_vector_type(8))) short  bfrag;   // 8 bf16 (4 VGPRs)
typedef __attribute__((ext_vector_type(4))) float  ffrag;   // 4 f32 acc

#define MFMA16(A,B,C) __builtin_amdgcn_mfma_f32_16x16x32_bf16((A),(B),(C),0,0,0)

__device__ __forceinline__ ffrag fzero() {
    ffrag z;
    z[0] = 0.f; z[1] = 0.f; z[2] = 0.f; z[3] = 0.f;
    return z;
}

__device__ __forceinline__ unsigned short f2bf(float f) {
    unsigned int u = __float_as_uint(f);
    u += 0x7FFFu + ((u >> 16) & 1u);          // round-to-nearest-even
    return (unsigned short)(u >> 16);
}
__device__ __forceinline__ float bf2f(unsigned short u) {
    return __uint_as_float(((unsigned int)u) << 16);
}

// ---------------------------------------------------------------------------
// Prep: cluster_center f32 [512][256] -> Cb bf16 [512][256], Ct bf16 [256][512],
// c_sq[512] (sum of squares of the bf16-rounded values).
// ---------------------------------------------------------------------------
__global__ void prep_kernel(const float* __restrict__ C,
                            unsigned short* __restrict__ Cb,
                            unsigned short* __restrict__ Ct,
                            float* __restrict__ csq)
{
    __shared__ unsigned short lds[64 * 264];
    const int tid = threadIdx.x;          // 256 threads
    const int kb  = blockIdx.x * 64;      // 8 blocks
    const int r   = tid >> 2;
    const int q   = tid & 3;

    const float* cr = C + (size_t)(kb + r) * D_DIM;
    float s = 0.f;
    #pragma unroll
    for (int i = 0; i < 16; ++i) {
        const int j = q * 16 + i;
        f4 v = *(const f4*)(cr + j * 4);
        unsigned short u0 = f2bf(v[0]), u1 = f2bf(v[1]), u2 = f2bf(v[2]), u3 = f2bf(v[3]);
        *(ushort4*)(Cb + (size_t)(kb + r) * D_DIM + j * 4) = make_ushort4(u0, u1, u2, u3);
        *(ushort4*)(lds + r * 264 + j * 4)                  = make_ushort4(u0, u1, u2, u3);
        float f0 = bf2f(u0), f1 = bf2f(u1), f2_ = bf2f(u2), f3 = bf2f(u3);
        s += f0 * f0 + f1 * f1 + f2_ * f2_ + f3 * f3;
    }
    s += __shfl_xor(s, 1, 64);
    s += __shfl_xor(s, 2, 64);
    if (q == 0) csq[kb + r] = s;
    __syncthreads();

    #pragma unroll
    for (int c = 0; c < 16; ++c) {
        ushort4 p = make_ushort4(lds[(c * 4 + 0) * 264 + tid],
                                 lds[(c * 4 + 1) * 264 + tid],
                                 lds[(c * 4 + 2) * 264 + tid],
                                 lds[(c * 4 + 3) * 264 + tid]);
        *(ushort4*)(Ct + (size_t)tid * K_CL + kb + c * 4) = p;
    }
}

// ---------------------------------------------------------------------------
// Fused: LN -> cdist -> softmax -> x_rec. 256 thr (4 waves), 32 rows/block.
// Swapped-operand MFMA: lane(g,cl) of wave w holds tile elem
// (row = rt*16+cl, col = w*128 + nt*16 + g*4 + r) => dwordx4 stores, 2-shuffle
// row-softmax. 3 barriers: GEMM2 runs on UNNORMALIZED p (bf16) and scales by
// rn at the end (x_rec linearity), so as_s + sumexp share one barrier.
// Registers uncapped: compiler prefetches B-streams (the R1 lesson).
// ---------------------------------------------------------------------------
__global__ __launch_bounds__(256)
void fused_kernel(const float* __restrict__ x,
                  const float* __restrict__ lnw,
                  const float* __restrict__ lnb,
                  const unsigned short* __restrict__ Cb,
                  const unsigned short* __restrict__ Ct,
                  const float* __restrict__ csq,
                  float* __restrict__ out0,   // x_distance  [M][512]
                  float* __restrict__ out1,   // assign      [M][512]
                  float* __restrict__ out2)   // x_rec       [M][256]
{
    __shared__ __align__(16) char smem[34432];
    // [0, 33280): xn_s [32][264] bf16 (16896B) UNION as_s [32][520] bf16 (33280B)
    // xn_s dead after GEMM1 (all waves past it at barrier 2); as_s written in
    // phase D (after barrier 2), read in GEMM2 (after barrier 3).
    unsigned short* xn_s = (unsigned short*)smem;
    unsigned short* as_s = (unsigned short*)smem;
    float* red_a = (float*)(smem + 33280);    // [2][4][16] f32 (512B)
    float* red_b = (float*)(smem + 33792);    // [2][4][16] f32 (512B)
    float* xsq_s = (float*)(smem + 34304);    // [32]

    const int tid = threadIdx.x;
    const int w   = tid >> 6;        // wave 0..3
    const int l   = tid & 63;
    const int g   = l >> 4;          // 16-lane group
    const int cl  = l & 15;
    const int m0  = blockIdx.x * 32;
    const int nb  = w * 128;         // GEMM1 col base
    const int db  = w * 64;          // GEMM2 col base

    // ---- Phase A: LayerNorm (8 lanes per row) ----
    {
        const int rr = tid >> 3, sub = tid & 7;
        const float* xr = x + (size_t)(m0 + rr) * D_DIM;
        f4 xv[8];
        float sum = 0.f, ss = 0.f;
        #pragma unroll
        for (int i = 0; i < 8; ++i) {
            xv[i] = *(const f4*)(xr + (i * 8 + sub) * 4);
            #pragma unroll
            for (int c = 0; c < 4; ++c) { float v = xv[i][c]; sum += v; ss += v * v; }
        }
        #pragma unroll
        for (int msk = 1; msk < 8; msk <<= 1) {
            sum += __shfl_xor(sum, msk, 64);
            ss  += __shfl_xor(ss,  msk, 64);
        }
        const float mean = sum * (1.0f / 256.0f);
        float var = ss * (1.0f / 256.0f) - mean * mean;
        var = fmaxf(var, 0.0f);
        const float inv = 1.0f / (sqrtf(var) + 1e-5f);

        float xsq = 0.f;
        #pragma unroll
        for (int i = 0; i < 8; ++i) {
            f4 wv = *(const f4*)(lnw + (i * 8 + sub) * 4);
            f4 bv = *(const f4*)(lnb + (i * 8 + sub) * 4);
            float a0 = (xv[i][0] - mean) * inv * wv[0] + bv[0];
            float a1 = (xv[i][1] - mean) * inv * wv[1] + bv[1];
            float a2 = (xv[i][2] - mean) * inv * wv[2] + bv[2];
            float a3 = (xv[i][3] - mean) * inv * wv[3] + bv[3];
            unsigned short u0 = f2bf(a0), u1 = f2bf(a1), u2 = f2bf(a2), u3 = f2bf(a3);
            float c0 = bf2f(u0), c1 = bf2f(u1), c2 = bf2f(u2), c3 = bf2f(u3);
            xsq += c0 * c0 + c1 * c1 + c2 * c2 + c3 * c3;
            *(ushort4*)(xn_s + rr * 264 + (i * 8 + sub) * 4) = make_ushort4(u0, u1, u2, u3);
        }
        #pragma unroll
        for (int msk = 1; msk < 8; msk <<= 1) xsq += __shfl_xor(xsq, msk, 64);
        if (sub == 0) xsq_s[rr] = xsq;
    }
    __syncthreads();                               // barrier 1

    // ---- Phase A2: GEMM1 (swapped). acc[rt][nt] covers rows rt*16+cl,
    //      cols nb+nt*16+g*4+r. Cb streamed (dbuf), xn from LDS. ----
    ffrag acc[2][8];
    #pragma unroll
    for (int rt = 0; rt < 2; ++rt)
        #pragma unroll
        for (int nt = 0; nt < 8; ++nt) acc[rt][nt] = fzero();
    {
        bfrag cb[2][4];
        #pragma unroll
        for (int i = 0; i < 4; ++i)
            cb[0][i] = *(const bfrag*)(Cb + (nb + cl) * D_DIM + i * 32 + g * 8);
        #pragma unroll
        for (int bi = 0; bi < 16; ++bi) {
            const int nt = bi >> 1, kh = bi & 1;
            if (bi < 15) {
                const int nn = (bi + 1) >> 1, nk = (bi + 1) & 1;
                #pragma unroll
                for (int i = 0; i < 4; ++i)
                    cb[(bi + 1) & 1][i] = *(const bfrag*)
                        (Cb + (nb + nn * 16 + cl) * D_DIM + (nk * 4 + i) * 32 + g * 8);
            }
            #pragma unroll
            for (int rt = 0; rt < 2; ++rt)
                #pragma unroll
                for (int i = 0; i < 4; ++i) {
                    bfrag xf = *(const bfrag*)
                        (xn_s + (rt * 16 + cl) * 264 + (kh * 4 + i) * 32 + g * 8);
                    acc[rt][nt] = MFMA16(cb[bi & 1][i], xf, acc[rt][nt]);
                }
        }
    }

    // ---- Phase B: distances, dwordx4 stores, row sums ----
    float dsum[2];
    dsum[0] = 0.f; dsum[1] = 0.f;
    {
        const float xsqv0 = xsq_s[cl];
        const float xsqv1 = xsq_s[16 + cl];
        #pragma unroll
        for (int nt = 0; nt < 8; ++nt) {
            f4 cs = *(const f4*)(csq + nb + nt * 16 + g * 4);
            #pragma unroll
            for (int rt = 0; rt < 2; ++rt) {
                const float xsqv = rt ? xsqv1 : xsqv0;
                f4 dv;
                #pragma unroll
                for (int r = 0; r < 4; ++r) {
                    float d2 = xsqv + cs[r] - 2.0f * acc[rt][nt][r];
                    dv[r] = sqrtf(fmaxf(d2, 0.0f));
                    acc[rt][nt][r] = dv[r];
                }
                *(f4*)(out0 + (size_t)(m0 + rt * 16 + cl) * K_CL + nb + nt * 16 + g * 4) = dv;
                dsum[rt] += dv[0] + dv[1] + dv[2] + dv[3];
            }
        }
    }
    #pragma unroll
    for (int rt = 0; rt < 2; ++rt) {
        dsum[rt] += __shfl_xor(dsum[rt], 16, 64);
        dsum[rt] += __shfl_xor(dsum[rt], 32, 64);
    }
    if (l < 16) {
        red_a[w * 16 + cl]      = dsum[0];
        red_a[64 + w * 16 + cl] = dsum[1];
    }
    __syncthreads();                               // barrier 2

    float sc[2];
    #pragma unroll
    for (int rt = 0; rt < 2; ++rt) {
        float t = red_a[rt * 64 + cl] + red_a[rt * 64 + 16 + cl]
                + red_a[rt * 64 + 32 + cl] + red_a[rt * 64 + 48 + cl];
        sc[rt] = 16384.0f / t;                     // alpha*K/sum = 32/mean_d
    }

    // ---- Phase D: p = exp(-d*sc) (unnormalized), es partials, p->as_s bf16.
    //      No max-sub: logits ~ -32, f32/bf16-safe (p ~ 1e-13, scale-free). ----
    float es[2];
    #pragma unroll
    for (int rt = 0; rt < 2; ++rt) {
        es[rt] = 0.f;
        #pragma unroll
        for (int nt = 0; nt < 8; ++nt) {
            f4 pv;
            #pragma unroll
            for (int r = 0; r < 4; ++r) {
                float p = __expf(-acc[rt][nt][r] * sc[rt]);
                acc[rt][nt][r] = p;
                pv[r] = p;
                es[rt] += p;
            }
            unsigned int lo = (unsigned int)f2bf(pv[0]) | ((unsigned int)f2bf(pv[1]) << 16);
            unsigned int hi = (unsigned int)f2bf(pv[2]) | ((unsigned int)f2bf(pv[3]) << 16);
            *(uint2*)(as_s + (rt * 16 + cl) * 520 + nb + nt * 16 + g * 4) =
                make_uint2(lo, hi);
        }
        es[rt] += __shfl_xor(es[rt], 16, 64);
        es[rt] += __shfl_xor(es[rt], 32, 64);
    }
    if (l < 16) {
        red_b[w * 16 + cl]      = es[0];
        red_b[64 + w * 16 + cl] = es[1];
    }
    __syncthreads();                               // barrier 3 (es + as_s ready)

    float rn[2];
    #pragma unroll
    for (int rt = 0; rt < 2; ++rt) {
        rn[rt] = 1.0f / (red_b[rt * 64 + cl] + red_b[rt * 64 + 16 + cl]
                       + red_b[rt * 64 + 32 + cl] + red_b[rt * 64 + 48 + cl]);
    }

    // ---- Phase D2: out1 = p * rn (dwordx4 stores, from registers) ----
    #pragma unroll
    for (int rt = 0; rt < 2; ++rt)
        #pragma unroll
        for (int nt = 0; nt < 8; ++nt) {
            f4 av;
            #pragma unroll
            for (int r = 0; r < 4; ++r) av[r] = acc[rt][nt][r] * rn[rt];
            *(f4*)(out1 + (size_t)(m0 + rt * 16 + cl) * K_CL + nb + nt * 16 + g * 4) = av;
        }

    // ---- Phase E: GEMM2 on unnormalized p; scale by rn at store.
    //      acc2[rt][nt] covers rows rt*16+cl, d-cols db+nt*16+g*4+r. ----
    {
        ffrag acc2[2][4];
        #pragma unroll
        for (int rt = 0; rt < 2; ++rt)
            #pragma unroll
            for (int nt = 0; nt < 4; ++nt) acc2[rt][nt] = fzero();

        bfrag ct[2][4];
        #pragma unroll
        for (int i = 0; i < 4; ++i)
            ct[0][i] = *(const bfrag*)(Ct + (db + cl) * K_CL + i * 32 + g * 8);
        #pragma unroll
        for (int bi = 0; bi < 16; ++bi) {
            const int nt = bi >> 2, kb = bi & 3;
            if (bi < 15) {
                const int nn = (bi + 1) >> 2, nk = (bi + 1) & 3;
                #pragma unroll
                for (int i = 0; i < 4; ++i)
                    ct[(bi + 1) & 1][i] = *(const bfrag*)
                        (Ct + (db + nn * 16 + cl) * K_CL + (nk * 4 + i) * 32 + g * 8);
            }
            #pragma unroll
            for (int rt = 0; rt < 2; ++rt)
                #pragma unroll
                for (int i = 0; i < 4; ++i) {
                    bfrag af = *(const bfrag*)
                        (as_s + (rt * 16 + cl) * 520 + (kb * 4 + i) * 32 + g * 8);
                    acc2[rt][nt] = MFMA16(ct[bi & 1][i], af, acc2[rt][nt]);
                }
        }

        #pragma unroll
        for (int rt = 0; rt < 2; ++rt)
            #pragma unroll
            for (int nt = 0; nt < 4; ++nt) {
                f4 rv;
                #pragma unroll
                for (int r = 0; r < 4; ++r) rv[r] = acc2[rt][nt][r] * rn[rt];
                *(f4*)(out2 + (size_t)(m0 + rt * 16 + cl) * D_DIM + db + nt * 16 + g * 4) = rv;
            }
    }
}

extern "C" void kernel_launch(void* const* d_in, const int* in_sizes, int n_in,
                              void* d_out, int out_size, void* d_ws, size_t ws_size,
                              hipStream_t stream)
{
    const float* x   = (const float*)d_in[0];
    const float* lnw = (const float*)d_in[1];
    const float* lnb = (const float*)d_in[2];
    const float* C   = (const float*)d_in[3];

    float* out0 = (float*)d_out;
    float* out1 = out0 + (size_t)M_ROWS * K_CL;
    float* out2 = out1 + (size_t)M_ROWS * K_CL;

    unsigned short* Cb = (unsigned short*)d_ws;                       // 512*256 bf16
    unsigned short* Ct = Cb + (size_t)K_CL * D_DIM;                   // 256*512 bf16
    float*          cs = (float*)((char*)d_ws + 2u * K_CL * D_DIM * 2u); // [512] f32

    prep_kernel<<<8, 256, 0, stream>>>(C, Cb, Ct, cs);
    fused_kernel<<<M_ROWS / 32, 256, 0, stream>>>(x, lnw, lnb, Cb, Ct, cs,
                                                  out0, out1, out2);
}